// Round 2
// baseline (219.091 us; speedup 1.0000x reference)
//
#include <hip/hip_runtime.h>
#include <math.h>

// MultiSimilarityLoss B=8192 D=128, R7 (= R6 resubmit + workspace hardening;
// R6 bench was an infra failure, no counters returned).
// Counting-sort rows by label => same-label pairs are block-diagonal. Each
// 16x16 MFMA tile is then classified wave-uniformly (scalar label compares)
// as pure-negative (~97%), pure-positive, or mixed; pure tiles run collapsed
// epilogues (ms1: 1 running max; ms2: fma+exp+cmp+add), removing the ~11
// VALU/elem mask machinery that made R5 VALU-bound (MfmaUtil 12.5%).
// Also: exp folded to raw v_exp_f32 (log2-domain coefficients), stage-1
// partial fold hoisted into ms_bounds, jsplit=64 when workspace allows.
// Hardening vs R6: dstmap aliases psum (dead until ms2); jsplit=32 fallback
// footprint ~6.2 MB (R5 used 6 MB and fit).

#define B_N  8192
#define DDIM 128
#define JT   16              // j-tile rows per iteration
#define NG   4               // 16-col i-groups per wave (64 i per wave)

typedef __attribute__((ext_vector_type(8))) short bf16x8;  // 8 bf16 = 4 VGPRs
typedef __attribute__((ext_vector_type(4))) float f32x4;

static constexpr float ONE_EPS  = 1.0f - 1e-5f;
static constexpr float F_MARGIN = 0.1f;
// exp in log2 domain: exp(a*s+b) = exp2(s*a*log2e + b*log2e)
static constexpr float KP2A = -2.8853900817779268f;   // -2 * log2(e)
static constexpr float KP2B =  1.4426950408889634f;   //  1 * log2(e)
static constexpr float KN2A =  57.707801635558536f;   // 40 * log2(e)
static constexpr float KN2B = -28.853900817779268f;   // -20 * log2(e)

__device__ __forceinline__ float exp2_fast(float x) {
#if __has_builtin(__builtin_amdgcn_exp2f)
    return __builtin_amdgcn_exp2f(x);
#else
    return __expf(x * 0.6931471805599453f);
#endif
}

// ---------------------------------------------------------------- histogram + prefix
__global__ __launch_bounds__(256)
void ms_hist(const int* __restrict__ labels, int* __restrict__ cursors)
{
    __shared__ int cnt[128];
    const int tid = threadIdx.x;
    if (tid < 128) cnt[tid] = 0;
    __syncthreads();
    for (int r = tid; r < B_N; r += 256) atomicAdd(&cnt[labels[r]], 1);
    __syncthreads();
    if (tid == 0) {
        int run = 0;
        for (int l = 0; l < 128; ++l) { cursors[l] = run; run += cnt[l]; }
    }
}

// ---------------------------------------------------------------- rank scatter
__global__ __launch_bounds__(256)
void ms_dstmap(const int* __restrict__ labels, int* __restrict__ cursors,
               int* __restrict__ dstmap, int* __restrict__ plab)
{
    const int r = blockIdx.x * 256 + threadIdx.x;
    const int l = labels[r];
    const int dst = atomicAdd(&cursors[l], 1);  // within-class order irrelevant
    dstmap[r] = dst;
    plab[dst] = l;                              // sorted (non-decreasing) labels
}

// ---------------------------------------------------------------- permute + cast fp32->bf16 (RNE)
__global__ __launch_bounds__(256)
void ms_permcast(const float* __restrict__ f, const int* __restrict__ dstmap,
                 ushort* __restrict__ fb)
{
    const int i4  = (blockIdx.x * 256 + threadIdx.x) * 4;
    const int r   = i4 >> 7;           // / DDIM
    const int col = i4 & (DDIM - 1);
    const int dst = dstmap[r];
    float4 v = *(const float4*)(f + i4);
    ushort4 o;
    uint u;
    u = __float_as_uint(v.x); o.x = (ushort)((u + 0x7fffu + ((u >> 16) & 1u)) >> 16);
    u = __float_as_uint(v.y); o.y = (ushort)((u + 0x7fffu + ((u >> 16) & 1u)) >> 16);
    u = __float_as_uint(v.z); o.z = (ushort)((u + 0x7fffu + ((u >> 16) & 1u)) >> 16);
    u = __float_as_uint(v.w); o.w = (ushort)((u + 0x7fffu + ((u >> 16) & 1u)) >> 16);
    *(ushort4*)(fb + dst * DDIM + col) = o;
}

// ---------------------------------------------------------------- stage 1: min_pos / max_neg
__global__ __launch_bounds__(256, 4)
void ms1(const ushort* __restrict__ fb, const int* __restrict__ lab,
         float* __restrict__ minp_part, float* __restrict__ maxn_part,
         const int jrange)
{
    const int tid  = threadIdx.x;
    const int w    = tid >> 6;
    const int lane = tid & 63;
    const int q    = lane >> 4;      // quad: k-chunk (operands) / j-rows (output)
    const int c    = lane & 15;      // i within 16-group (output col)
    const int i0   = blockIdx.x * 256;
    const int j0   = blockIdx.y * jrange;
    const int iw0  = i0 + w * 64;
    const int njt  = jrange / JT;

    // persistent i-side fragments (B operand): 64 i per wave, K=128
    bf16x8 ifr[NG][4];
    int    li[NG], glf[NG], gll[NG];
    #pragma unroll
    for (int g = 0; g < NG; ++g) {
        int row = iw0 + g * 16 + c;
        #pragma unroll
        for (int ks = 0; ks < 4; ++ks)
            ifr[g][ks] = *(const bf16x8*)(fb + row * DDIM + ks * 32 + q * 8);
        li[g]  = lab[row];
        glf[g] = lab[iw0 + g * 16];        // uniform: first/last label of i-group
        gll[g] = lab[iw0 + g * 16 + 15];
    }

    float vmin[NG], vmax[NG];
    #pragma unroll
    for (int g = 0; g < NG; ++g) { vmin[g] = INFINITY; vmax[g] = -INFINITY; }

    #pragma unroll 1
    for (int jt = 0; jt < njt; ++jt) {
        const int jb = j0 + jt * JT;
        bf16x8 jfr[4];                       // streamed j-side (A operand)
        #pragma unroll
        for (int ks = 0; ks < 4; ++ks)
            jfr[ks] = *(const bf16x8*)(fb + (jb + c) * DDIM + ks * 32 + q * 8);

        const int ljf = lab[jb], ljl = lab[jb + 15];   // uniform
        bool pn[NG], pp[NG];
        bool anyMixed = false;
        #pragma unroll
        for (int g = 0; g < NG; ++g) {
            pn[g] = (gll[g] < ljf) || (ljl < glf[g]);                       // disjoint labels
            pp[g] = (glf[g] == gll[g]) && (ljf == ljl) && (glf[g] == ljf); // one common label
            anyMixed = anyMixed || (!pn[g] && !pp[g]);
        }
        int4 lj = {0, 0, 0, 0};
        if (anyMixed) lj = *(const int4*)(lab + jb + q * 4);

        #pragma unroll
        for (int g = 0; g < NG; ++g) {
            f32x4 acc = {0.f, 0.f, 0.f, 0.f};
            #pragma unroll
            for (int ks = 0; ks < 4; ++ks)
                acc = __builtin_amdgcn_mfma_f32_16x16x32_bf16(jfr[ks], ifr[g][ks], acc, 0, 0, 0);
            // D: row (j) = q*4 + r, col (i) = c
            if (pn[g]) {            // all negatives: just the running max
                vmax[g] = fmaxf(vmax[g],
                                fmaxf(fmaxf(acc[0], acc[1]), fmaxf(acc[2], acc[3])));
            } else if (pp[g]) {     // all positives: running min with s<1-eps filter
                #pragma unroll
                for (int r = 0; r < 4; ++r) {
                    float s = acc[r];
                    vmin[g] = fminf(vmin[g], s < ONE_EPS ? s : INFINITY);
                }
            } else {                // mixed tile: general path
                #pragma unroll
                for (int r = 0; r < 4; ++r) {
                    float s = acc[r];
                    int ljr = (r == 0) ? lj.x : (r == 1) ? lj.y : (r == 2) ? lj.z : lj.w;
                    bool same = (li[g] == ljr);
                    vmin[g] = fminf(vmin[g], (same && s < ONE_EPS) ? s : INFINITY);
                    vmax[g] = fmaxf(vmax[g], same ? -INFINITY : s);
                }
            }
        }
    }

    #pragma unroll
    for (int g = 0; g < NG; ++g) {
        vmin[g] = fminf(vmin[g], __shfl_xor(vmin[g], 16, 64));
        vmin[g] = fminf(vmin[g], __shfl_xor(vmin[g], 32, 64));
        vmax[g] = fmaxf(vmax[g], __shfl_xor(vmax[g], 16, 64));
        vmax[g] = fmaxf(vmax[g], __shfl_xor(vmax[g], 32, 64));
    }
    if (q == 0) {
        #pragma unroll
        for (int g = 0; g < NG; ++g) {
            int row = iw0 + g * 16 + c;
            minp_part[blockIdx.y * B_N + row] = vmin[g];
            maxn_part[blockIdx.y * B_N + row] = vmax[g];
        }
    }
}

// ---------------------------------------------------------------- fold partials -> bounds
__global__ __launch_bounds__(256)
void ms_bounds(const float* __restrict__ minp_part, const float* __restrict__ maxn_part,
               float* __restrict__ pb, float* __restrict__ nb, const int jsplit)
{
    const int i = blockIdx.x * 256 + threadIdx.x;
    float mn = INFINITY, mx = -INFINITY;
    for (int s = 0; s < jsplit; ++s) {
        mn = fminf(mn, minp_part[s * B_N + i]);
        mx = fmaxf(mx, maxn_part[s * B_N + i]);
    }
    pb[i] = fminf(ONE_EPS, mx + F_MARGIN);   // pos kept iff s < pb  (-inf if no negs)
    nb[i] = mn - F_MARGIN;                   // neg kept iff s >= nb (+inf if no poss)
}

// ---------------------------------------------------------------- stage 2: masked exp sums
__global__ __launch_bounds__(256, 4)
void ms2(const ushort* __restrict__ fb, const int* __restrict__ lab,
         const float* __restrict__ pb, const float* __restrict__ nb,
         float* __restrict__ psum_part, float* __restrict__ nsum_part,
         const int jrange)
{
    const int tid  = threadIdx.x;
    const int w    = tid >> 6;
    const int lane = tid & 63;
    const int q    = lane >> 4;
    const int c    = lane & 15;
    const int i0   = blockIdx.x * 256;
    const int j0   = blockIdx.y * jrange;
    const int iw0  = i0 + w * 64;
    const int njt  = jrange / JT;

    bf16x8 ifr[NG][4];
    int    li[NG], glf[NG], gll[NG];
    float  pbv[NG], nbv[NG];
    #pragma unroll
    for (int g = 0; g < NG; ++g) {
        int row = iw0 + g * 16 + c;
        #pragma unroll
        for (int ks = 0; ks < 4; ++ks)
            ifr[g][ks] = *(const bf16x8*)(fb + row * DDIM + ks * 32 + q * 8);
        li[g]  = lab[row];
        glf[g] = lab[iw0 + g * 16];
        gll[g] = lab[iw0 + g * 16 + 15];
        pbv[g] = pb[row];
        nbv[g] = nb[row];
    }

    float ps[NG], ns[NG];
    #pragma unroll
    for (int g = 0; g < NG; ++g) { ps[g] = 0.f; ns[g] = 0.f; }

    #pragma unroll 1
    for (int jt = 0; jt < njt; ++jt) {
        const int jb = j0 + jt * JT;
        bf16x8 jfr[4];
        #pragma unroll
        for (int ks = 0; ks < 4; ++ks)
            jfr[ks] = *(const bf16x8*)(fb + (jb + c) * DDIM + ks * 32 + q * 8);

        const int ljf = lab[jb], ljl = lab[jb + 15];
        bool pn[NG], pp[NG];
        bool anyMixed = false;
        #pragma unroll
        for (int g = 0; g < NG; ++g) {
            pn[g] = (gll[g] < ljf) || (ljl < glf[g]);
            pp[g] = (glf[g] == gll[g]) && (ljf == ljl) && (glf[g] == ljf);
            anyMixed = anyMixed || (!pn[g] && !pp[g]);
        }
        int4 lj = {0, 0, 0, 0};
        if (anyMixed) lj = *(const int4*)(lab + jb + q * 4);

        #pragma unroll
        for (int g = 0; g < NG; ++g) {
            f32x4 acc = {0.f, 0.f, 0.f, 0.f};
            #pragma unroll
            for (int ks = 0; ks < 4; ++ks)
                acc = __builtin_amdgcn_mfma_f32_16x16x32_bf16(jfr[ks], ifr[g][ks], acc, 0, 0, 0);
            if (pn[g]) {            // all negatives
                #pragma unroll
                for (int r = 0; r < 4; ++r) {
                    float s = acc[r];
                    float e = exp2_fast(fmaf(s, KN2A, KN2B));
                    ns[g] += (s >= nbv[g]) ? e : 0.0f;
                }
            } else if (pp[g]) {     // all positives
                #pragma unroll
                for (int r = 0; r < 4; ++r) {
                    float s = acc[r];
                    float e = exp2_fast(fmaf(s, KP2A, KP2B));
                    ps[g] += (s < pbv[g]) ? e : 0.0f;
                }
            } else {                // mixed
                #pragma unroll
                for (int r = 0; r < 4; ++r) {
                    float s = acc[r];
                    int ljr = (r == 0) ? lj.x : (r == 1) ? lj.y : (r == 2) ? lj.z : lj.w;
                    bool same = (li[g] == ljr);
                    float e = exp2_fast(fmaf(s, same ? KP2A : KN2A, same ? KP2B : KN2B));
                    bool lt = s < (same ? pbv[g] : nbv[g]);
                    ps[g] += (same && lt)   ? e : 0.0f;
                    ns[g] += (!same && !lt) ? e : 0.0f;
                }
            }
        }
    }

    #pragma unroll
    for (int g = 0; g < NG; ++g) {
        ps[g] += __shfl_xor(ps[g], 16, 64);
        ps[g] += __shfl_xor(ps[g], 32, 64);
        ns[g] += __shfl_xor(ns[g], 16, 64);
        ns[g] += __shfl_xor(ns[g], 32, 64);
    }
    if (q == 0) {
        #pragma unroll
        for (int g = 0; g < NG; ++g) {
            int row = iw0 + g * 16 + c;
            psum_part[blockIdx.y * B_N + row] = ps[g];
            nsum_part[blockIdx.y * B_N + row] = ns[g];
        }
    }
}

// ---------------------------------------------------------------- finalize
__global__ __launch_bounds__(256)
void ms_fin(const float* __restrict__ psum_part, const float* __restrict__ nsum_part,
            const float* __restrict__ pb, const float* __restrict__ nb,
            float* __restrict__ out, const int jsplit)
{
    const int i = blockIdx.x * 256 + threadIdx.x;
    float ps = 0.f, ns = 0.f;
    for (int s = 0; s < jsplit; ++s) {
        ps += psum_part[s * B_N + i];
        ns += nsum_part[s * B_N + i];
    }
    float rl = 0.f;
    // valid: has_pos (nb<inf), has_neg (pb>-inf), nonempty stage-2 sets
    if (nb[i] < INFINITY && pb[i] > -INFINITY && ps > 0.f && ns > 0.f)
        rl = log1pf(ps) * 0.5f + log1pf(ns) * 0.025f;   // /SCALE_POS, /SCALE_NEG

    #pragma unroll
    for (int off = 32; off > 0; off >>= 1) rl += __shfl_down(rl, off, 64);
    __shared__ float wsum[4];
    int lane = threadIdx.x & 63, wv = threadIdx.x >> 6;
    if (lane == 0) wsum[wv] = rl;
    __syncthreads();
    if (threadIdx.x == 0)
        atomicAdd(out, (wsum[0] + wsum[1] + wsum[2] + wsum[3]) * (1.0f / (float)B_N));
}

// ---------------------------------------------------------------- launch
extern "C" void kernel_launch(void* const* d_in, const int* in_sizes, int n_in,
                              void* d_out, int out_size, void* d_ws, size_t ws_size,
                              hipStream_t stream)
{
    const float* feats  = (const float*)d_in[0];
    const int*   labels = (const int*)d_in[1];

    // Fixed small tail: pb/nb (64KB) + plab (32KB) + cursors (512B)
    const size_t tail = 2 * (size_t)B_N * 4 + (size_t)B_N * 4 + 1024;
    const size_t need64 = (size_t)B_N * DDIM * 2 + 4ull * 64 * B_N * 4 + tail;
    const int jsplit = (ws_size == 0 || ws_size >= need64) ? 64 : 32;
    const int jrange = B_N / jsplit;

    char* p = (char*)d_ws;
    ushort* fb     = (ushort*)p;  p += (size_t)B_N * DDIM * 2;      // 2 MB (permuted bf16)
    float* minp    = (float*)p;   p += (size_t)jsplit * B_N * 4;
    float* maxn    = (float*)p;   p += (size_t)jsplit * B_N * 4;
    float* psum    = (float*)p;   p += (size_t)jsplit * B_N * 4;
    float* nsum    = (float*)p;   p += (size_t)jsplit * B_N * 4;
    float* pbb     = (float*)p;   p += (size_t)B_N * 4;
    float* nbb     = (float*)p;   p += (size_t)B_N * 4;
    int*   plab    = (int*)p;     p += (size_t)B_N * 4;
    int*   cursors = (int*)p;     p += 128 * 4;
    int*   dstmap  = (int*)psum;  // alias: psum is dead until ms2

    hipMemsetAsync(d_out, 0, sizeof(float), stream);

    ms_hist<<<1, 256, 0, stream>>>(labels, cursors);
    ms_dstmap<<<B_N / 256, 256, 0, stream>>>(labels, cursors, dstmap, plab);
    ms_permcast<<<(B_N * DDIM) / (256 * 4), 256, 0, stream>>>(feats, dstmap, fb);
    ms1<<<dim3(B_N / 256, jsplit), 256, 0, stream>>>(fb, plab, minp, maxn, jrange);
    ms_bounds<<<B_N / 256, 256, 0, stream>>>(minp, maxn, pbb, nbb, jsplit);
    ms2<<<dim3(B_N / 256, jsplit), 256, 0, stream>>>(fb, plab, pbb, nbb, psum, nsum, jrange);
    ms_fin<<<B_N / 256, 256, 0, stream>>>(psum, nsum, pbb, nbb, (float*)d_out, jsplit);
}